// Round 14
// baseline (303.261 us; speedup 1.0000x reference)
//
#include <hip/hip_runtime.h>
#include <math.h>

// Problem constants (reference: N=256, H=512, K=2048, B=256, ETA=1.0)
#define NSEQ 256
#define HDIM 512
#define KDS  2048
#define BB   256
#define NM   255   // N-1 prefix rows

typedef __attribute__((ext_vector_type(8))) short bf16x8;
typedef __attribute__((ext_vector_type(4))) float f32x4;
typedef long i64;

// ---------------- workspace layout (float slots) ----------------
#define OFF_ACC   0            //        16
#define OFF_PMAX  16           // 2,088,960  per (m,b,32 k-groups) max
#define OFF_PSUM  2088976      // 2,088,960  sumexp
#define OFF_PARG  4177936      // 2,088,960  argmax (int)
#define OFF_PTGT  6266896      //    65,280  target logit per (m,b)
#define OFF_DSB   6332176      //   524,288 ushort = bf16 dataset [k][n]
#define OFF_SEQB  6594320      //    65,536 ushort = bf16 seq [b][j]
#define OFF_WBB   6627088      //   131,072 ushort = bf16 softmax(B_logits) [h][n]
#define OFF_PHI8  6692624      // 1,048,576 bytes = fp8 phi [h/8][k][8]
#define OFF_HAT8  6954768      // 33,423,360 bytes = fp8 hat [m][b][h]
// end: 15,310,608 floats = 61.2 MB (< 140 MB proven available)

__device__ __forceinline__ ushort f2bf(float f) {
    unsigned u = __float_as_uint(f);
    unsigned r = (u + 0x7fffu + ((u >> 16) & 1u)) >> 16;   // RNE; NaN impossible here
    return (ushort)r;
}

// f32 -> OCP e4m3fn, RNE, saturating (values here are |x| <= ~1)
__device__ __forceinline__ unsigned char f2e4m3(float f) {
    unsigned u = __float_as_uint(f);
    unsigned s = (u >> 24) & 0x80;
    int e = (int)((u >> 23) & 0xff) - 127;
    unsigned m = u & 0x7fffff;
    if (e >= 9) return (unsigned char)(s | 0x7e);          // saturate 448
    if (e >= -6) {                                         // normal
        unsigned keep = m >> 20;
        unsigned rest = m & 0xfffff;
        keep += (rest > 0x80000u) || (rest == 0x80000u && (keep & 1));
        unsigned v = ((unsigned)(e + 7) << 3) + keep;      // carry ok
        if (v > 0x7e) v = 0x7e;
        return (unsigned char)(s | v);
    }
    if (e < -9) return (unsigned char)s;                   // -> 0
    unsigned full = 0x800000u | m;                         // subnormal
    int sh = 20 + (-6 - e);
    unsigned keep = full >> sh;
    unsigned rem = full & ((1u << sh) - 1);
    unsigned half = 1u << (sh - 1);
    keep += (rem > half) || (rem == half && (keep & 1));
    return (unsigned char)(s | (keep > 7 ? 8 : keep));
}

__global__ void kzero(float* a) {
    if (threadIdx.x < 16) a[threadIdx.x] = 0.0f;
}

// convert dataset (K,N) and sequences (B,N) f32 -> bf16, same layouts
__global__ __launch_bounds__(256) void kernT2(const float* __restrict__ ds,
                                              const float* __restrict__ seq,
                                              ushort* __restrict__ dsb,
                                              ushort* __restrict__ seqb) {
    int id = blockIdx.x * 256 + threadIdx.x;      // grid covers KDS*NSEQ exactly
    dsb[id] = f2bf(ds[id]);
    if (id < BB * NSEQ) seqb[id] = f2bf(seq[id]);
}

// softmax each row of B_logits (512 x 256) -> bf16 wBb [h][n]
__global__ __launch_bounds__(256) void kernSB(const float* __restrict__ B_logits,
                                              ushort* __restrict__ wBb) {
    int w = threadIdx.x >> 6, l = threadIdx.x & 63;
    int h = blockIdx.x * 4 + w;
    float4 v = ((const float4*)(B_logits + (size_t)h * NSEQ))[l];
    float mx = fmaxf(fmaxf(v.x, v.y), fmaxf(v.z, v.w));
    #pragma unroll
    for (int off = 32; off; off >>= 1) mx = fmaxf(mx, __shfl_xor(mx, off));
    float e[4] = {__expf(v.x - mx), __expf(v.y - mx), __expf(v.z - mx), __expf(v.w - mx)};
    float s = e[0] + e[1] + e[2] + e[3];
    #pragma unroll
    for (int off = 32; off; off >>= 1) s += __shfl_xor(s, off);
    float inv = 1.0f / s;
    uint2 o;
    o.x = (unsigned)f2bf(e[0] * inv) | ((unsigned)f2bf(e[1] * inv) << 16);
    o.y = (unsigned)f2bf(e[2] * inv) | ((unsigned)f2bf(e[3] * inv) << 16);
    *(uint2*)(wBb + (size_t)h * NSEQ + l * 4) = o;
}

// phi GEMM: phi[k][h] = sum_n dsb[k][n] * wBb[h][n]; epilogue writes fp8 phi8:
// phi8[((h>>3)*KDS + k)*8 + (h&7)] so kernD's B-fragment loads are 8B contiguous.
#define LDST 144
__global__ __launch_bounds__(256) void kernP(const ushort* __restrict__ dsb,
                                             const ushort* __restrict__ wBb,
                                             unsigned char* __restrict__ phi8) {
    int kblk = blockIdx.x, hblk = blockIdx.y;
    int t = threadIdx.x, lane = t & 63, wave = t >> 6;
    int bhalf = wave & 1, khalf = wave >> 1;
    __shared__ int4 Al4[128 * LDST / 16];
    __shared__ int4 Bl4[128 * LDST / 16];
    char* Al = (char*)Al4;
    char* Bl = (char*)Bl4;
    f32x4 acc[4][4];
    #pragma unroll
    for (int mb = 0; mb < 4; ++mb)
        #pragma unroll
        for (int nk = 0; nk < 4; ++nk) acc[mb][nk] = (f32x4){0.f, 0.f, 0.f, 0.f};
    const ushort* Abase = dsb + (size_t)kblk * 128 * NSEQ;
    const ushort* Bbase = wBb + (size_t)hblk * 128 * NSEQ;
    int l15 = lane & 15, lg = lane >> 4;
    for (int n0 = 0; n0 < NSEQ; n0 += 64) {
        #pragma unroll
        for (int i = 0; i < 4; ++i) {
            int c = i * 256 + t;
            int row = c >> 3, c8 = c & 7;
            int4 va = *(const int4*)(Abase + (size_t)row * NSEQ + n0 + c8 * 8);
            int4 vb = *(const int4*)(Bbase + (size_t)row * NSEQ + n0 + c8 * 8);
            *(int4*)(Al + row * LDST + c8 * 16) = va;
            *(int4*)(Bl + row * LDST + c8 * 16) = vb;
        }
        __syncthreads();
        #pragma unroll
        for (int ks = 0; ks < 2; ++ks) {
            bf16x8 fa[4], fb[4];
            #pragma unroll
            for (int mb = 0; mb < 4; ++mb)
                fa[mb] = *(const bf16x8*)(Al + (bhalf * 64 + mb * 16 + l15) * LDST + ks * 64 + lg * 16);
            #pragma unroll
            for (int nk = 0; nk < 4; ++nk)
                fb[nk] = *(const bf16x8*)(Bl + (khalf * 64 + nk * 16 + l15) * LDST + ks * 64 + lg * 16);
            #pragma unroll
            for (int mb = 0; mb < 4; ++mb)
                #pragma unroll
                for (int nk = 0; nk < 4; ++nk)
                    acc[mb][nk] = __builtin_amdgcn_mfma_f32_16x16x32_bf16(fa[mb], fb[nk], acc[mb][nk], 0, 0, 0);
        }
        __syncthreads();
    }
    #pragma unroll
    for (int mb = 0; mb < 4; ++mb)
        #pragma unroll
        for (int r = 0; r < 4; ++r) {
            int k = kblk * 128 + bhalf * 64 + mb * 16 + lg * 4 + r;
            #pragma unroll
            for (int nk = 0; nk < 4; ++nk) {
                int h = hblk * 128 + khalf * 64 + nk * 16 + l15;
                phi8[((size_t)(h >> 3) * KDS + k) * 8 + (h & 7)] = f2e4m3(acc[mb][nk][r]);
            }
        }
}

// Fused: masked softmax of A_logits[m+1, ht*128..+128, :] -> bf16 weights in LDS,
// then MFMA  hat[b][h] = sum_j seq[b][j] * W[h][j]  -> hat8 fp8 [m][b][h].
__global__ __launch_bounds__(512) void kernC2(const float* __restrict__ A_logits,
                                              const ushort* __restrict__ seqb,
                                              unsigned char* __restrict__ hat8) {
    int m = blockIdx.x, ht = blockIdx.y;
    int t = threadIdx.x, lane = t & 63, wave = t >> 6;
    int bq = wave & 3, hhalf = wave >> 2;
    int l15 = lane & 15, lg = lane >> 4;
    __shared__ int4 Wl4[128 * 512 / 16];   // 64 KB
    char* Wl = (char*)Wl4;

    for (int rr = 0; rr < 16; ++rr) {
        int hl = wave + rr * 8;
        const float4* row = (const float4*)(A_logits + ((size_t)(m + 1) * HDIM + ht * 128 + hl) * NSEQ);
        float4 v = row[lane];
        int j0 = lane * 4;
        float x[4];
        x[0] = (j0 + 0 <= m) ? v.x : -INFINITY;
        x[1] = (j0 + 1 <= m) ? v.y : -INFINITY;
        x[2] = (j0 + 2 <= m) ? v.z : -INFINITY;
        x[3] = (j0 + 3 <= m) ? v.w : -INFINITY;
        float mx = fmaxf(fmaxf(x[0], x[1]), fmaxf(x[2], x[3]));
        #pragma unroll
        for (int off = 32; off; off >>= 1) mx = fmaxf(mx, __shfl_xor(mx, off));
        float e[4], s = 0.0f;
        #pragma unroll
        for (int q = 0; q < 4; ++q) {
            e[q] = (x[q] > -INFINITY) ? __expf(x[q] - mx) : 0.0f;
            s += e[q];
        }
        #pragma unroll
        for (int off = 32; off; off >>= 1) s += __shfl_xor(s, off);
        float inv = 1.0f / s;
        uint2 wv;
        wv.x = (unsigned)f2bf(e[0] * inv) | ((unsigned)f2bf(e[1] * inv) << 16);
        wv.y = (unsigned)f2bf(e[2] * inv) | ((unsigned)f2bf(e[3] * inv) << 16);
        int wo = (lane * 8) ^ ((hl & 7) << 4);
        *(uint2*)(Wl + hl * 512 + wo) = wv;
    }
    __syncthreads();

    f32x4 acc[4][4];
    #pragma unroll
    for (int mb = 0; mb < 4; ++mb)
        #pragma unroll
        for (int nk = 0; nk < 4; ++nk) acc[mb][nk] = (f32x4){0.f, 0.f, 0.f, 0.f};

    #pragma unroll
    for (int ks = 0; ks < 8; ++ks) {
        bf16x8 fa[4], fb[4];
        #pragma unroll
        for (int mb = 0; mb < 4; ++mb)
            fa[mb] = *(const bf16x8*)(seqb + (size_t)(bq * 64 + mb * 16 + l15) * NSEQ + ks * 32 + lg * 8);
        #pragma unroll
        for (int nk = 0; nk < 4; ++nk) {
            int hrow = hhalf * 64 + nk * 16 + l15;
            int co = (ks * 64 + lg * 16) ^ ((hrow & 7) << 4);
            fb[nk] = *(const bf16x8*)(Wl + hrow * 512 + co);
        }
        #pragma unroll
        for (int mb = 0; mb < 4; ++mb)
            #pragma unroll
            for (int nk = 0; nk < 4; ++nk)
                acc[mb][nk] = __builtin_amdgcn_mfma_f32_16x16x32_bf16(fa[mb], fb[nk], acc[mb][nk], 0, 0, 0);
    }

    #pragma unroll
    for (int mb = 0; mb < 4; ++mb)
        #pragma unroll
        for (int r = 0; r < 4; ++r) {
            int b = bq * 64 + mb * 16 + lg * 4 + r;
            #pragma unroll
            for (int nk = 0; nk < 4; ++nk) {
                int h = ht * 128 + hhalf * 64 + nk * 16 + l15;
                hat8[((size_t)m * BB + b) * HDIM + h] = f2e4m3(acc[mb][nk][r]);
            }
        }
}

// Logits GEMM, fp8, barrier-free: A = 64 b-rows x 512 h fp8 in LDS (32 KB,
// reg-staged once, granule-XOR swizzle g8^((row&3)<<2) -> free-minimum 4-way),
// B fragments = 8B L2 loads from phi8, 1-deep x/y register prefetch.
// mfma_f32_16x16x32_fp8_fp8 (bf16 rate, half the fragment bytes).
__global__ __launch_bounds__(512, 4) void kernD(const unsigned char* __restrict__ hat8,
                                                const unsigned char* __restrict__ phi8,
                                                const int* __restrict__ indices,
                                                float* __restrict__ pmax,
                                                float* __restrict__ psum,
                                                int* __restrict__ parg,
                                                float* __restrict__ ptgt) {
    // XCD-chunked decode: 16 consecutive blocks (one m) per XCD position
    int id = blockIdx.x;                    // 0..4079
    int c = id & 7, pos = id >> 3;
    int lin = c * 510 + pos;                // bijective (4080 = 8*510)
    int m = lin >> 4, sub = lin & 15;
    int bblk = sub >> 2, kblk = sub & 3;

    int t = threadIdx.x, l = t & 63, w = t >> 6;   // w = k-slice index
    int l15 = l & 15, lg = l >> 4;

    __shared__ char Al[64 * 512];           // 32 KB fp8 A panel
    __shared__ int idx_s[64];

    // one-time A stage (reg-staged, swizzled): 64 rows x 512B
    const unsigned char* Ab = hat8 + ((size_t)m * BB + bblk * 64) * HDIM;
    #pragma unroll
    for (int i = 0; i < 4; ++i) {
        int row = w * 8 + i * 2 + (l >> 5);
        int col16 = l & 31;
        int4 v = *(const int4*)(Ab + (size_t)row * 512 + col16 * 16);
        int gx = (col16 * 2) ^ ((row & 3) << 2);
        *(int4*)(Al + row * 512 + gx * 8) = v;
    }
    if (t < 64) idx_s[t] = indices[bblk * 64 + t];
    __syncthreads();

    int kb = kblk * 512 + w * 64;           // this wave's k base
    const unsigned char* Bp = phi8 + ((size_t)lg * KDS + kb + l15) * 8;

    f32x4 acc[4][4];
    #pragma unroll
    for (int mb = 0; mb < 4; ++mb)
        #pragma unroll
        for (int nk = 0; nk < 4; ++nk) acc[mb][nk] = (f32x4){0.f, 0.f, 0.f, 0.f};

    i64 nb0 = *(const i64*)(Bp);
    i64 nb1 = *(const i64*)(Bp + 128);
    i64 nb2 = *(const i64*)(Bp + 256);
    i64 nb3 = *(const i64*)(Bp + 384);

    int swz = ((l15 & 3) << 2);             // row&3 == l15&3 for all mb

    #pragma unroll
    for (int kstep = 0; kstep < 16; ++kstep) {
        i64 fb0 = nb0, fb1 = nb1, fb2 = nb2, fb3 = nb3;
        if (kstep < 15) {
            Bp += 65536;                    // 4*KDS*8 bytes
            nb0 = *(const i64*)(Bp);
            nb1 = *(const i64*)(Bp + 128);
            nb2 = *(const i64*)(Bp + 256);
            nb3 = *(const i64*)(Bp + 384);
        }
        int gx = (kstep * 4 + lg) ^ swz;
        i64 fa[4];
        #pragma unroll
        for (int mb = 0; mb < 4; ++mb)
            fa[mb] = *(const i64*)(Al + (mb * 16 + l15) * 512 + gx * 8);
        #pragma unroll
        for (int mb = 0; mb < 4; ++mb) {
            acc[mb][0] = __builtin_amdgcn_mfma_f32_16x16x32_fp8_fp8(fa[mb], fb0, acc[mb][0], 0, 0, 0);
            acc[mb][1] = __builtin_amdgcn_mfma_f32_16x16x32_fp8_fp8(fa[mb], fb1, acc[mb][1], 0, 0, 0);
            acc[mb][2] = __builtin_amdgcn_mfma_f32_16x16x32_fp8_fp8(fa[mb], fb2, acc[mb][2], 0, 0, 0);
            acc[mb][3] = __builtin_amdgcn_mfma_f32_16x16x32_fp8_fp8(fa[mb], fb3, acc[mb][3], 0, 0, 0);
        }
    }

    // epilogue: two-pass per b-row (max -> sumexp), cndmask argmax, 1 ptgt store
    #pragma unroll
    for (int mb = 0; mb < 4; ++mb) {
        #pragma unroll
        for (int r = 0; r < 4; ++r) {
            int row_local = mb * 16 + lg * 4 + r;         // 0..63
            int bg = bblk * 64 + row_local;               // b 0..255
            int ib = idx_s[row_local];
            float a0 = acc[mb][0][r], a1 = acc[mb][1][r];
            float a2 = acc[mb][2][r], a3 = acc[mb][3][r];
            float M = fmaxf(fmaxf(a0, a1), fmaxf(a2, a3));
            #pragma unroll
            for (int off = 1; off < 16; off <<= 1) M = fmaxf(M, __shfl_xor(M, off));
            float S = __expf(a0 - M) + __expf(a1 - M) + __expf(a2 - M) + __expf(a3 - M);
            #pragma unroll
            for (int off = 1; off < 16; off <<= 1) S += __shfl_xor(S, off);
            int KA = 0x7fffffff;
            KA = (a3 == M) ? (kb + 48 + l15) : KA;
            KA = (a2 == M) ? (kb + 32 + l15) : KA;
            KA = (a1 == M) ? (kb + 16 + l15) : KA;
            KA = (a0 == M) ? (kb + l15) : KA;
            #pragma unroll
            for (int off = 1; off < 16; off <<= 1) {
                int ok = __shfl_xor(KA, off);
                KA = ok < KA ? ok : KA;
            }
            int d = ib - kb;
            if ((unsigned)d < 64u && (d & 15) == l15) {
                float s0 = (d & 16) ? a1 : a0;
                float s1 = (d & 16) ? a3 : a2;
                ptgt[m * BB + bg] = (d & 32) ? s1 : s0;
            }
            if (l15 == 0) {
                size_t pidx = ((size_t)m * BB + bg) * 32 + kblk * 8 + w;   // ascending k
                pmax[pidx] = M;
                psum[pidx] = S;
                parg[pidx] = KA;
            }
            __builtin_amdgcn_sched_barrier(0);
        }
    }
}

// combine 32 k-range partials per (m,b) -> CE + accuracy sums
__global__ __launch_bounds__(256) void kernE(const float* __restrict__ pmax,
                                             const float* __restrict__ psum,
                                             const int* __restrict__ parg,
                                             const float* __restrict__ ptgt,
                                             const int* __restrict__ indices,
                                             float* __restrict__ accum) {
    int m = blockIdx.x, b = threadIdx.x;
    size_t base = ((size_t)m * BB + b) * 32;
    float M = -INFINITY, S = 0.0f;
    int KA = 0;
    #pragma unroll 4
    for (int kb = 0; kb < 32; ++kb) {       // ascending k: strict > keeps first-index ties
        float om = pmax[base + kb], os = psum[base + kb];
        int ok = parg[base + kb];
        float Mn = fmaxf(M, om);
        S = S * __expf(M - Mn) + os * __expf(om - Mn);
        if (om > M) KA = ok;
        M = Mn;
    }
    float ce = M + logf(S) - ptgt[(size_t)m * BB + b];
    float corr = (KA == indices[b]) ? 1.0f : 0.0f;
    #pragma unroll
    for (int off = 32; off; off >>= 1) { ce += __shfl_xor(ce, off); corr += __shfl_xor(corr, off); }
    __shared__ float rc[4], rr[4];
    int wv = b >> 6;
    if ((b & 63) == 0) { rc[wv] = ce; rr[wv] = corr; }
    __syncthreads();
    if (b == 0) {
        atomicAdd(&accum[0], rc[0] + rc[1] + rc[2] + rc[3]);
        atomicAdd(&accum[1], rr[0] + rr[1] + rr[2] + rr[3]);
    }
}

__global__ void kfin(const float* __restrict__ accum, float* __restrict__ out) {
    if (threadIdx.x == 0) {
        const float inv = 1.0f / (255.0f * 256.0f);
        out[0] = accum[0] * inv;
        out[1] = accum[1] * inv;
    }
}

extern "C" void kernel_launch(void* const* d_in, const int* in_sizes, int n_in,
                              void* d_out, int out_size, void* d_ws, size_t ws_size,
                              hipStream_t stream) {
    const float* A_logits = (const float*)d_in[0];   // (256,512,256)
    const float* B_logits = (const float*)d_in[1];   // (512,256)
    const float* sequences = (const float*)d_in[2];  // (256,256)
    const float* dataset = (const float*)d_in[3];    // (2048,256)
    const int* indices = (const int*)d_in[4];        // (256,)
    float* out = (float*)d_out;

    float* ws = (float*)d_ws;
    float* accum = ws + OFF_ACC;
    float* pmax = ws + OFF_PMAX;
    float* psum = ws + OFF_PSUM;
    int* parg = (int*)(ws + OFF_PARG);
    float* ptgt = ws + OFF_PTGT;
    ushort* dsb = (ushort*)(ws + OFF_DSB);
    ushort* seqb = (ushort*)(ws + OFF_SEQB);
    ushort* wBb = (ushort*)(ws + OFF_WBB);
    unsigned char* phi8 = (unsigned char*)(ws + OFF_PHI8);
    unsigned char* hat8 = (unsigned char*)(ws + OFF_HAT8);

    kzero<<<1, 64, 0, stream>>>(accum);
    kernT2<<<(KDS * NSEQ) / 256, 256, 0, stream>>>(dataset, sequences, dsb, seqb);
    kernSB<<<HDIM / 4, 256, 0, stream>>>(B_logits, wBb);
    kernP<<<dim3(KDS / 128, HDIM / 128), 256, 0, stream>>>(dsb, wBb, phi8);
    kernC2<<<dim3(NM, HDIM / 128), 512, 0, stream>>>(A_logits, seqb, hat8);
    kernD<<<NM * 16, 512, 0, stream>>>(hat8, phi8, indices, pmax, psum, parg, ptgt);
    kernE<<<NM, 256, 0, stream>>>(pmax, psum, parg, ptgt, indices, accum);
    kfin<<<1, 64, 0, stream>>>(accum, out);
}

// Round 15
// 225.170 us; speedup vs baseline: 1.3468x; 1.3468x over previous
//
#include <hip/hip_runtime.h>
#include <math.h>

// Problem constants (reference: N=256, H=512, K=2048, B=256, ETA=1.0)
#define NSEQ 256
#define HDIM 512
#define KDS  2048
#define BB   256
#define NM   255   // N-1 prefix rows

typedef __attribute__((ext_vector_type(8))) short bf16x8;
typedef __attribute__((ext_vector_type(4))) float f32x4;
typedef long i64;

// ---------------- workspace layout (float slots) ----------------
#define OFF_ACC   0            //        16
#define OFF_PMAX  16           // 2,088,960  per (m,b,32 k-groups) max
#define OFF_PSUM  2088976      // 2,088,960  sumexp
#define OFF_PARG  4177936      // 2,088,960  argmax (int)
#define OFF_PTGT  6266896      //    65,280  target logit per (m,b)
#define OFF_DSB   6332176      //   524,288 ushort = bf16 dataset [k][n]
#define OFF_SEQB  6594320      //    65,536 ushort = bf16 seq [b][j]
#define OFF_WBB   6627088      //   131,072 ushort = bf16 softmax(B_logits) [h][n]
#define OFF_PHI8  6692624      // 1,048,576 bytes = fp8 phi [h/8][k][8]
#define OFF_HAT8  6954768      // 33,423,360 bytes = fp8 hat [m][b][h]
// end: 15,310,608 floats = 61.2 MB (< 140 MB proven available)

__device__ __forceinline__ ushort f2bf(float f) {
    unsigned u = __float_as_uint(f);
    unsigned r = (u + 0x7fffu + ((u >> 16) & 1u)) >> 16;   // RNE; NaN impossible here
    return (ushort)r;
}

// HW fp8 e4m3fn convert: 2 floats -> 2 bytes (low word), RNE
__device__ __forceinline__ unsigned cvtpk8(float a, float b) {
    return (unsigned)__builtin_amdgcn_cvt_pk_fp8_f32(a, b, 0, false);
}

__global__ void kzero(float* a) {
    if (threadIdx.x < 16) a[threadIdx.x] = 0.0f;
}

// convert dataset (K,N) and sequences (B,N) f32 -> bf16, same layouts
__global__ __launch_bounds__(256) void kernT2(const float* __restrict__ ds,
                                              const float* __restrict__ seq,
                                              ushort* __restrict__ dsb,
                                              ushort* __restrict__ seqb) {
    int id = blockIdx.x * 256 + threadIdx.x;      // grid covers KDS*NSEQ exactly
    dsb[id] = f2bf(ds[id]);
    if (id < BB * NSEQ) seqb[id] = f2bf(seq[id]);
}

// softmax each row of B_logits (512 x 256) -> bf16 wBb [h][n]
__global__ __launch_bounds__(256) void kernSB(const float* __restrict__ B_logits,
                                              ushort* __restrict__ wBb) {
    int w = threadIdx.x >> 6, l = threadIdx.x & 63;
    int h = blockIdx.x * 4 + w;
    float4 v = ((const float4*)(B_logits + (size_t)h * NSEQ))[l];
    float mx = fmaxf(fmaxf(v.x, v.y), fmaxf(v.z, v.w));
    #pragma unroll
    for (int off = 32; off; off >>= 1) mx = fmaxf(mx, __shfl_xor(mx, off));
    float e[4] = {__expf(v.x - mx), __expf(v.y - mx), __expf(v.z - mx), __expf(v.w - mx)};
    float s = e[0] + e[1] + e[2] + e[3];
    #pragma unroll
    for (int off = 32; off; off >>= 1) s += __shfl_xor(s, off);
    float inv = 1.0f / s;
    uint2 o;
    o.x = (unsigned)f2bf(e[0] * inv) | ((unsigned)f2bf(e[1] * inv) << 16);
    o.y = (unsigned)f2bf(e[2] * inv) | ((unsigned)f2bf(e[3] * inv) << 16);
    *(uint2*)(wBb + (size_t)h * NSEQ + l * 4) = o;
}

// phi GEMM: phi[k][h] = sum_n dsb[k][n] * wBb[h][n]; epilogue writes fp8 phi8:
// phi8[((h>>3)*KDS + k)*8 + (h&7)] so kernD's B-fragment loads are 8B contiguous.
#define LDST 144
__global__ __launch_bounds__(256) void kernP(const ushort* __restrict__ dsb,
                                             const ushort* __restrict__ wBb,
                                             unsigned char* __restrict__ phi8) {
    int kblk = blockIdx.x, hblk = blockIdx.y;
    int t = threadIdx.x, lane = t & 63, wave = t >> 6;
    int bhalf = wave & 1, khalf = wave >> 1;
    __shared__ int4 Al4[128 * LDST / 16];
    __shared__ int4 Bl4[128 * LDST / 16];
    char* Al = (char*)Al4;
    char* Bl = (char*)Bl4;
    f32x4 acc[4][4];
    #pragma unroll
    for (int mb = 0; mb < 4; ++mb)
        #pragma unroll
        for (int nk = 0; nk < 4; ++nk) acc[mb][nk] = (f32x4){0.f, 0.f, 0.f, 0.f};
    const ushort* Abase = dsb + (size_t)kblk * 128 * NSEQ;
    const ushort* Bbase = wBb + (size_t)hblk * 128 * NSEQ;
    int l15 = lane & 15, lg = lane >> 4;
    for (int n0 = 0; n0 < NSEQ; n0 += 64) {
        #pragma unroll
        for (int i = 0; i < 4; ++i) {
            int c = i * 256 + t;
            int row = c >> 3, c8 = c & 7;
            int4 va = *(const int4*)(Abase + (size_t)row * NSEQ + n0 + c8 * 8);
            int4 vb = *(const int4*)(Bbase + (size_t)row * NSEQ + n0 + c8 * 8);
            *(int4*)(Al + row * LDST + c8 * 16) = va;
            *(int4*)(Bl + row * LDST + c8 * 16) = vb;
        }
        __syncthreads();
        #pragma unroll
        for (int ks = 0; ks < 2; ++ks) {
            bf16x8 fa[4], fb[4];
            #pragma unroll
            for (int mb = 0; mb < 4; ++mb)
                fa[mb] = *(const bf16x8*)(Al + (bhalf * 64 + mb * 16 + l15) * LDST + ks * 64 + lg * 16);
            #pragma unroll
            for (int nk = 0; nk < 4; ++nk)
                fb[nk] = *(const bf16x8*)(Bl + (khalf * 64 + nk * 16 + l15) * LDST + ks * 64 + lg * 16);
            #pragma unroll
            for (int mb = 0; mb < 4; ++mb)
                #pragma unroll
                for (int nk = 0; nk < 4; ++nk)
                    acc[mb][nk] = __builtin_amdgcn_mfma_f32_16x16x32_bf16(fa[mb], fb[nk], acc[mb][nk], 0, 0, 0);
        }
        __syncthreads();
    }
    #pragma unroll
    for (int mb = 0; mb < 4; ++mb)
        #pragma unroll
        for (int r = 0; r < 4; ++r) {
            int k = kblk * 128 + bhalf * 64 + mb * 16 + lg * 4 + r;
            unsigned p01 = cvtpk8(acc[mb][0][r], acc[mb][1][r]);
            unsigned p23 = cvtpk8(acc[mb][2][r], acc[mb][3][r]);
            #pragma unroll
            for (int nk = 0; nk < 4; ++nk) {
                int h = hblk * 128 + khalf * 64 + nk * 16 + l15;
                unsigned byte = (nk < 2) ? ((nk & 1) ? (p01 >> 8) : p01)
                                         : ((nk & 1) ? (p23 >> 8) : p23);
                phi8[((size_t)(h >> 3) * KDS + k) * 8 + (h & 7)] = (unsigned char)(byte & 0xff);
            }
        }
}

// Fused: masked softmax of A_logits[m+1, ht*128..+128, :] -> bf16 weights in LDS,
// then MFMA  hat[b][h] = sum_j seq[b][j] * W[h][j]  -> hat8 fp8 [m][b][h].
__global__ __launch_bounds__(512) void kernC2(const float* __restrict__ A_logits,
                                              const ushort* __restrict__ seqb,
                                              unsigned char* __restrict__ hat8) {
    int m = blockIdx.x, ht = blockIdx.y;
    int t = threadIdx.x, lane = t & 63, wave = t >> 6;
    int bq = wave & 3, hhalf = wave >> 2;
    int l15 = lane & 15, lg = lane >> 4;
    __shared__ int4 Wl4[128 * 512 / 16];   // 64 KB
    char* Wl = (char*)Wl4;

    for (int rr = 0; rr < 16; ++rr) {
        int hl = wave + rr * 8;
        const float4* row = (const float4*)(A_logits + ((size_t)(m + 1) * HDIM + ht * 128 + hl) * NSEQ);
        float4 v = row[lane];
        int j0 = lane * 4;
        float x[4];
        x[0] = (j0 + 0 <= m) ? v.x : -INFINITY;
        x[1] = (j0 + 1 <= m) ? v.y : -INFINITY;
        x[2] = (j0 + 2 <= m) ? v.z : -INFINITY;
        x[3] = (j0 + 3 <= m) ? v.w : -INFINITY;
        float mx = fmaxf(fmaxf(x[0], x[1]), fmaxf(x[2], x[3]));
        #pragma unroll
        for (int off = 32; off; off >>= 1) mx = fmaxf(mx, __shfl_xor(mx, off));
        float e[4], s = 0.0f;
        #pragma unroll
        for (int q = 0; q < 4; ++q) {
            e[q] = (x[q] > -INFINITY) ? __expf(x[q] - mx) : 0.0f;
            s += e[q];
        }
        #pragma unroll
        for (int off = 32; off; off >>= 1) s += __shfl_xor(s, off);
        float inv = 1.0f / s;
        uint2 wv;
        wv.x = (unsigned)f2bf(e[0] * inv) | ((unsigned)f2bf(e[1] * inv) << 16);
        wv.y = (unsigned)f2bf(e[2] * inv) | ((unsigned)f2bf(e[3] * inv) << 16);
        int wo = (lane * 8) ^ ((hl & 7) << 4);
        *(uint2*)(Wl + hl * 512 + wo) = wv;
    }
    __syncthreads();

    f32x4 acc[4][4];
    #pragma unroll
    for (int mb = 0; mb < 4; ++mb)
        #pragma unroll
        for (int nk = 0; nk < 4; ++nk) acc[mb][nk] = (f32x4){0.f, 0.f, 0.f, 0.f};

    #pragma unroll
    for (int ks = 0; ks < 8; ++ks) {
        bf16x8 fa[4], fb[4];
        #pragma unroll
        for (int mb = 0; mb < 4; ++mb)
            fa[mb] = *(const bf16x8*)(seqb + (size_t)(bq * 64 + mb * 16 + l15) * NSEQ + ks * 32 + lg * 8);
        #pragma unroll
        for (int nk = 0; nk < 4; ++nk) {
            int hrow = hhalf * 64 + nk * 16 + l15;
            int co = (ks * 64 + lg * 16) ^ ((hrow & 7) << 4);
            fb[nk] = *(const bf16x8*)(Wl + hrow * 512 + co);
        }
        #pragma unroll
        for (int mb = 0; mb < 4; ++mb)
            #pragma unroll
            for (int nk = 0; nk < 4; ++nk)
                acc[mb][nk] = __builtin_amdgcn_mfma_f32_16x16x32_bf16(fa[mb], fb[nk], acc[mb][nk], 0, 0, 0);
    }

    #pragma unroll
    for (int mb = 0; mb < 4; ++mb)
        #pragma unroll
        for (int r = 0; r < 4; ++r) {
            int b = bq * 64 + mb * 16 + lg * 4 + r;
            size_t base = ((size_t)m * BB + b) * HDIM + ht * 128 + hhalf * 64 + l15;
            unsigned p01 = cvtpk8(acc[mb][0][r], acc[mb][1][r]);
            unsigned p23 = cvtpk8(acc[mb][2][r], acc[mb][3][r]);
            hat8[base +  0] = (unsigned char)(p01 & 0xff);
            hat8[base + 16] = (unsigned char)((p01 >> 8) & 0xff);
            hat8[base + 32] = (unsigned char)(p23 & 0xff);
            hat8[base + 48] = (unsigned char)((p23 >> 8) & 0xff);
        }
}

// Logits GEMM, fp8, barrier-free: A = 64 b-rows x 512 h fp8 in LDS (32 KB,
// reg-staged once, full 4-bit granule swizzle gx = g ^ (row&15): every 16-lane
// phase hits all 16 bank-pairs -> conflict-free). B fragments = 8B L2 loads
// from phi8, 1-deep x/y prefetch. mfma_f32_16x16x32_fp8_fp8.
__global__ __launch_bounds__(512, 4) void kernD(const unsigned char* __restrict__ hat8,
                                                const unsigned char* __restrict__ phi8,
                                                const int* __restrict__ indices,
                                                float* __restrict__ pmax,
                                                float* __restrict__ psum,
                                                int* __restrict__ parg,
                                                float* __restrict__ ptgt) {
    // XCD-chunked decode: 16 consecutive blocks (one m) per XCD position
    int id = blockIdx.x;                    // 0..4079
    int c = id & 7, pos = id >> 3;
    int lin = c * 510 + pos;                // bijective (4080 = 8*510)
    int m = lin >> 4, sub = lin & 15;
    int bblk = sub >> 2, kblk = sub & 3;

    int t = threadIdx.x, l = t & 63, w = t >> 6;   // w = k-slice index
    int l15 = l & 15, lg = l >> 4;

    __shared__ char Al[64 * 512];           // 32 KB fp8 A panel
    __shared__ int idx_s[64];

    // one-time A stage (reg-staged): granule g of row r stored at gx = g^(r&15).
    // int4 covers granules {a, a+1} (a even); they land at pair {a^(r&14)} with
    // halves swapped when row is odd.
    const unsigned char* Ab = hat8 + ((size_t)m * BB + bblk * 64) * HDIM;
    #pragma unroll
    for (int i = 0; i < 4; ++i) {
        int row = w * 8 + i * 2 + (l >> 5);
        int col16 = l & 31;
        int4 v = *(const int4*)(Ab + (size_t)row * 512 + col16 * 16);
        if (row & 1) { int tx = v.x, ty = v.y; v.x = v.z; v.y = v.w; v.z = tx; v.w = ty; }
        int pairbase = (col16 * 2) ^ (row & 14);
        *(int4*)(Al + row * 512 + pairbase * 8) = v;
    }
    if (t < 64) idx_s[t] = indices[bblk * 64 + t];
    __syncthreads();

    int kb = kblk * 512 + w * 64;           // this wave's k base
    const unsigned char* Bp = phi8 + ((size_t)lg * KDS + kb + l15) * 8;

    f32x4 acc[4][4];
    #pragma unroll
    for (int mb = 0; mb < 4; ++mb)
        #pragma unroll
        for (int nk = 0; nk < 4; ++nk) acc[mb][nk] = (f32x4){0.f, 0.f, 0.f, 0.f};

    i64 nb0 = *(const i64*)(Bp);
    i64 nb1 = *(const i64*)(Bp + 128);
    i64 nb2 = *(const i64*)(Bp + 256);
    i64 nb3 = *(const i64*)(Bp + 384);

    #pragma unroll
    for (int kstep = 0; kstep < 16; ++kstep) {
        i64 fb0 = nb0, fb1 = nb1, fb2 = nb2, fb3 = nb3;
        if (kstep < 15) {
            Bp += 65536;                    // 4*KDS*8 bytes
            nb0 = *(const i64*)(Bp);
            nb1 = *(const i64*)(Bp + 128);
            nb2 = *(const i64*)(Bp + 256);
            nb3 = *(const i64*)(Bp + 384);
        }
        int gx = (kstep * 4 + lg) ^ l15;    // full 4-bit swizzle: conflict-free
        i64 fa[4];
        #pragma unroll
        for (int mb = 0; mb < 4; ++mb)
            fa[mb] = *(const i64*)(Al + (mb * 16 + l15) * 512 + gx * 8);
        #pragma unroll
        for (int mb = 0; mb < 4; ++mb) {
            acc[mb][0] = __builtin_amdgcn_mfma_f32_16x16x32_fp8_fp8(fa[mb], fb0, acc[mb][0], 0, 0, 0);
            acc[mb][1] = __builtin_amdgcn_mfma_f32_16x16x32_fp8_fp8(fa[mb], fb1, acc[mb][1], 0, 0, 0);
            acc[mb][2] = __builtin_amdgcn_mfma_f32_16x16x32_fp8_fp8(fa[mb], fb2, acc[mb][2], 0, 0, 0);
            acc[mb][3] = __builtin_amdgcn_mfma_f32_16x16x32_fp8_fp8(fa[mb], fb3, acc[mb][3], 0, 0, 0);
        }
    }

    // epilogue: two-pass per b-row (max -> sumexp), cndmask argmax, 1 ptgt store
    #pragma unroll
    for (int mb = 0; mb < 4; ++mb) {
        #pragma unroll
        for (int r = 0; r < 4; ++r) {
            int row_local = mb * 16 + lg * 4 + r;         // 0..63
            int bg = bblk * 64 + row_local;               // b 0..255
            int ib = idx_s[row_local];
            float a0 = acc[mb][0][r], a1 = acc[mb][1][r];
            float a2 = acc[mb][2][r], a3 = acc[mb][3][r];
            float M = fmaxf(fmaxf(a0, a1), fmaxf(a2, a3));
            #pragma unroll
            for (int off = 1; off < 16; off <<= 1) M = fmaxf(M, __shfl_xor(M, off));
            float S = __expf(a0 - M) + __expf(a1 - M) + __expf(a2 - M) + __expf(a3 - M);
            #pragma unroll
            for (int off = 1; off < 16; off <<= 1) S += __shfl_xor(S, off);
            int KA = 0x7fffffff;
            KA = (a3 == M) ? (kb + 48 + l15) : KA;
            KA = (a2 == M) ? (kb + 32 + l15) : KA;
            KA = (a1 == M) ? (kb + 16 + l15) : KA;
            KA = (a0 == M) ? (kb + l15) : KA;
            #pragma unroll
            for (int off = 1; off < 16; off <<= 1) {
                int ok = __shfl_xor(KA, off);
                KA = ok < KA ? ok : KA;
            }
            int d = ib - kb;
            if ((unsigned)d < 64u && (d & 15) == l15) {
                float s0 = (d & 16) ? a1 : a0;
                float s1 = (d & 16) ? a3 : a2;
                ptgt[m * BB + bg] = (d & 32) ? s1 : s0;
            }
            if (l15 == 0) {
                size_t pidx = ((size_t)m * BB + bg) * 32 + kblk * 8 + w;   // ascending k
                pmax[pidx] = M;
                psum[pidx] = S;
                parg[pidx] = KA;
            }
            __builtin_amdgcn_sched_barrier(0);
        }
    }
}

// combine 32 k-range partials per (m,b) -> CE + accuracy sums
__global__ __launch_bounds__(256) void kernE(const float* __restrict__ pmax,
                                             const float* __restrict__ psum,
                                             const int* __restrict__ parg,
                                             const float* __restrict__ ptgt,
                                             const int* __restrict__ indices,
                                             float* __restrict__ accum) {
    int m = blockIdx.x, b = threadIdx.x;
    size_t base = ((size_t)m * BB + b) * 32;
    float M = -INFINITY, S = 0.0f;
    int KA = 0;
    #pragma unroll 4
    for (int kb = 0; kb < 32; ++kb) {       // ascending k: strict > keeps first-index ties
        float om = pmax[base + kb], os = psum[base + kb];
        int ok = parg[base + kb];
        float Mn = fmaxf(M, om);
        S = S * __expf(M - Mn) + os * __expf(om - Mn);
        if (om > M) KA = ok;
        M = Mn;
    }
    float ce = M + logf(S) - ptgt[(size_t)m * BB + b];
    float corr = (KA == indices[b]) ? 1.0f : 0.0f;
    #pragma unroll
    for (int off = 32; off; off >>= 1) { ce += __shfl_xor(ce, off); corr += __shfl_xor(corr, off); }
    __shared__ float rc[4], rr[4];
    int wv = b >> 6;
    if ((b & 63) == 0) { rc[wv] = ce; rr[wv] = corr; }
    __syncthreads();
    if (b == 0) {
        atomicAdd(&accum[0], rc[0] + rc[1] + rc[2] + rc[3]);
        atomicAdd(&accum[1], rr[0] + rr[1] + rr[2] + rr[3]);
    }
}

__global__ void kfin(const float* __restrict__ accum, float* __restrict__ out) {
    if (threadIdx.x == 0) {
        const float inv = 1.0f / (255.0f * 256.0f);
        out[0] = accum[0] * inv;
        out[1] = accum[1] * inv;
    }
}

extern "C" void kernel_launch(void* const* d_in, const int* in_sizes, int n_in,
                              void* d_out, int out_size, void* d_ws, size_t ws_size,
                              hipStream_t stream) {
    const float* A_logits = (const float*)d_in[0];   // (256,512,256)
    const float* B_logits = (const float*)d_in[1];   // (512,256)
    const float* sequences = (const float*)d_in[2];  // (256,256)
    const float* dataset = (const float*)d_in[3];    // (2048,256)
    const int* indices = (const int*)d_in[4];        // (256,)
    float* out = (float*)d_out;

    float* ws = (float*)d_ws;
    float* accum = ws + OFF_ACC;
    float* pmax = ws + OFF_PMAX;
    float* psum = ws + OFF_PSUM;
    int* parg = (int*)(ws + OFF_PARG);
    float* ptgt = ws + OFF_PTGT;
    ushort* dsb = (ushort*)(ws + OFF_DSB);
    ushort* seqb = (ushort*)(ws + OFF_SEQB);
    ushort* wBb = (ushort*)(ws + OFF_WBB);
    unsigned char* phi8 = (unsigned char*)(ws + OFF_PHI8);
    unsigned char* hat8 = (unsigned char*)(ws + OFF_HAT8);

    kzero<<<1, 64, 0, stream>>>(accum);
    kernT2<<<(KDS * NSEQ) / 256, 256, 0, stream>>>(dataset, sequences, dsb, seqb);
    kernSB<<<HDIM / 4, 256, 0, stream>>>(B_logits, wBb);
    kernP<<<dim3(KDS / 128, HDIM / 128), 256, 0, stream>>>(dsb, wBb, phi8);
    kernC2<<<dim3(NM, HDIM / 128), 512, 0, stream>>>(A_logits, seqb, hat8);
    kernD<<<NM * 16, 512, 0, stream>>>(hat8, phi8, indices, pmax, psum, parg, ptgt);
    kernE<<<NM, 256, 0, stream>>>(pmax, psum, parg, ptgt, indices, accum);
    kfin<<<1, 64, 0, stream>>>(accum, out);
}

// Round 16
// 219.270 us; speedup vs baseline: 1.3830x; 1.0269x over previous
//
#include <hip/hip_runtime.h>
#include <math.h>

// Problem constants (reference: N=256, H=512, K=2048, B=256, ETA=1.0)
#define NSEQ 256
#define HDIM 512
#define KDS  2048
#define BB   256
#define NM   255   // N-1 prefix rows

typedef __attribute__((ext_vector_type(8))) short bf16x8;
typedef __attribute__((ext_vector_type(4))) float f32x4;
typedef long i64;
typedef __attribute__((ext_vector_type(2))) long i64x2;

// ---------------- workspace layout (float slots) ----------------
#define OFF_ACC   0            //        16
#define OFF_PMAX  16           // 2,088,960  per (m,b,32 k-groups) max
#define OFF_PSUM  2088976      // 2,088,960  sumexp
#define OFF_PARG  4177936      // 2,088,960  argmax (int)
#define OFF_PTGT  6266896      //    65,280  target logit per (m,b)
#define OFF_DSB   6332176      //   524,288 ushort = bf16 dataset [k][n]
#define OFF_SEQB  6594320      //    65,536 ushort = bf16 seq [b][j]
#define OFF_WBB   6627088      //   131,072 ushort = bf16 softmax(B_logits) [h][n]
#define OFF_PHI8  6692624      // 1,048,576 bytes = fp8 phi [h/8][kperm][8]
#define OFF_HAT8  6954768      // 33,423,360 bytes = fp8 hat [m][b][h]
// end: 15,310,608 floats = 61.2 MB (< 140 MB proven available)

__device__ __forceinline__ ushort f2bf(float f) {
    unsigned u = __float_as_uint(f);
    unsigned r = (u + 0x7fffu + ((u >> 16) & 1u)) >> 16;   // RNE; NaN impossible here
    return (ushort)r;
}

// HW fp8 e4m3fn convert: 2 floats -> 2 bytes (low word), RNE
__device__ __forceinline__ unsigned cvtpk8(float a, float b) {
    return (unsigned)__builtin_amdgcn_cvt_pk_fp8_f32(a, b, 0, false);
}

__global__ void kzero(float* a) {
    if (threadIdx.x < 16) a[threadIdx.x] = 0.0f;
}

// convert dataset (K,N) and sequences (B,N) f32 -> bf16, same layouts
__global__ __launch_bounds__(256) void kernT2(const float* __restrict__ ds,
                                              const float* __restrict__ seq,
                                              ushort* __restrict__ dsb,
                                              ushort* __restrict__ seqb) {
    int id = blockIdx.x * 256 + threadIdx.x;      // grid covers KDS*NSEQ exactly
    dsb[id] = f2bf(ds[id]);
    if (id < BB * NSEQ) seqb[id] = f2bf(seq[id]);
}

// softmax each row of B_logits (512 x 256) -> bf16 wBb [h][n]
__global__ __launch_bounds__(256) void kernSB(const float* __restrict__ B_logits,
                                              ushort* __restrict__ wBb) {
    int w = threadIdx.x >> 6, l = threadIdx.x & 63;
    int h = blockIdx.x * 4 + w;
    float4 v = ((const float4*)(B_logits + (size_t)h * NSEQ))[l];
    float mx = fmaxf(fmaxf(v.x, v.y), fmaxf(v.z, v.w));
    #pragma unroll
    for (int off = 32; off; off >>= 1) mx = fmaxf(mx, __shfl_xor(mx, off));
    float e[4] = {__expf(v.x - mx), __expf(v.y - mx), __expf(v.z - mx), __expf(v.w - mx)};
    float s = e[0] + e[1] + e[2] + e[3];
    #pragma unroll
    for (int off = 32; off; off >>= 1) s += __shfl_xor(s, off);
    float inv = 1.0f / s;
    uint2 o;
    o.x = (unsigned)f2bf(e[0] * inv) | ((unsigned)f2bf(e[1] * inv) << 16);
    o.y = (unsigned)f2bf(e[2] * inv) | ((unsigned)f2bf(e[3] * inv) << 16);
    *(uint2*)(wBb + (size_t)h * NSEQ + l * 4) = o;
}

// phi GEMM: phi[k][h] = sum_n dsb[k][n] * wBb[h][n]; epilogue writes fp8 phi8 at
// k-permuted position S(k) = (k&~31) + ((k&15)<<1) + ((k>>4)&1) so kernD's
// fb loads for nk=0,1 (and 2,3) are 16B contiguous -> dwordx4.
#define LDST 144
__global__ __launch_bounds__(256) void kernP(const ushort* __restrict__ dsb,
                                             const ushort* __restrict__ wBb,
                                             unsigned char* __restrict__ phi8) {
    int kblk = blockIdx.x, hblk = blockIdx.y;
    int t = threadIdx.x, lane = t & 63, wave = t >> 6;
    int bhalf = wave & 1, khalf = wave >> 1;
    __shared__ int4 Al4[128 * LDST / 16];
    __shared__ int4 Bl4[128 * LDST / 16];
    char* Al = (char*)Al4;
    char* Bl = (char*)Bl4;
    f32x4 acc[4][4];
    #pragma unroll
    for (int mb = 0; mb < 4; ++mb)
        #pragma unroll
        for (int nk = 0; nk < 4; ++nk) acc[mb][nk] = (f32x4){0.f, 0.f, 0.f, 0.f};
    const ushort* Abase = dsb + (size_t)kblk * 128 * NSEQ;
    const ushort* Bbase = wBb + (size_t)hblk * 128 * NSEQ;
    int l15 = lane & 15, lg = lane >> 4;
    for (int n0 = 0; n0 < NSEQ; n0 += 64) {
        #pragma unroll
        for (int i = 0; i < 4; ++i) {
            int c = i * 256 + t;
            int row = c >> 3, c8 = c & 7;
            int4 va = *(const int4*)(Abase + (size_t)row * NSEQ + n0 + c8 * 8);
            int4 vb = *(const int4*)(Bbase + (size_t)row * NSEQ + n0 + c8 * 8);
            *(int4*)(Al + row * LDST + c8 * 16) = va;
            *(int4*)(Bl + row * LDST + c8 * 16) = vb;
        }
        __syncthreads();
        #pragma unroll
        for (int ks = 0; ks < 2; ++ks) {
            bf16x8 fa[4], fb[4];
            #pragma unroll
            for (int mb = 0; mb < 4; ++mb)
                fa[mb] = *(const bf16x8*)(Al + (bhalf * 64 + mb * 16 + l15) * LDST + ks * 64 + lg * 16);
            #pragma unroll
            for (int nk = 0; nk < 4; ++nk)
                fb[nk] = *(const bf16x8*)(Bl + (khalf * 64 + nk * 16 + l15) * LDST + ks * 64 + lg * 16);
            #pragma unroll
            for (int mb = 0; mb < 4; ++mb)
                #pragma unroll
                for (int nk = 0; nk < 4; ++nk)
                    acc[mb][nk] = __builtin_amdgcn_mfma_f32_16x16x32_bf16(fa[mb], fb[nk], acc[mb][nk], 0, 0, 0);
        }
        __syncthreads();
    }
    #pragma unroll
    for (int mb = 0; mb < 4; ++mb)
        #pragma unroll
        for (int r = 0; r < 4; ++r) {
            int k = kblk * 128 + bhalf * 64 + mb * 16 + lg * 4 + r;
            int sk = (k & ~31) + ((k & 15) << 1) + ((k >> 4) & 1);   // bijective perm
            unsigned p01 = cvtpk8(acc[mb][0][r], acc[mb][1][r]);
            unsigned p23 = cvtpk8(acc[mb][2][r], acc[mb][3][r]);
            #pragma unroll
            for (int nk = 0; nk < 4; ++nk) {
                int h = hblk * 128 + khalf * 64 + nk * 16 + l15;
                unsigned byte = (nk < 2) ? ((nk & 1) ? (p01 >> 8) : p01)
                                         : ((nk & 1) ? (p23 >> 8) : p23);
                phi8[((size_t)(h >> 3) * KDS + sk) * 8 + (h & 7)] = (unsigned char)(byte & 0xff);
            }
        }
}

// Fused: masked softmax of A_logits[m+1, ht*128..+128, :] -> bf16 weights in LDS,
// then MFMA  hat[b][h] = sum_j seq[b][j] * W[h][j]  -> hat8 fp8 [m][b][h].
__global__ __launch_bounds__(512) void kernC2(const float* __restrict__ A_logits,
                                              const ushort* __restrict__ seqb,
                                              unsigned char* __restrict__ hat8) {
    int m = blockIdx.x, ht = blockIdx.y;
    int t = threadIdx.x, lane = t & 63, wave = t >> 6;
    int bq = wave & 3, hhalf = wave >> 2;
    int l15 = lane & 15, lg = lane >> 4;
    __shared__ int4 Wl4[128 * 512 / 16];   // 64 KB
    char* Wl = (char*)Wl4;

    for (int rr = 0; rr < 16; ++rr) {
        int hl = wave + rr * 8;
        const float4* row = (const float4*)(A_logits + ((size_t)(m + 1) * HDIM + ht * 128 + hl) * NSEQ);
        float4 v = row[lane];
        int j0 = lane * 4;
        float x[4];
        x[0] = (j0 + 0 <= m) ? v.x : -INFINITY;
        x[1] = (j0 + 1 <= m) ? v.y : -INFINITY;
        x[2] = (j0 + 2 <= m) ? v.z : -INFINITY;
        x[3] = (j0 + 3 <= m) ? v.w : -INFINITY;
        float mx = fmaxf(fmaxf(x[0], x[1]), fmaxf(x[2], x[3]));
        #pragma unroll
        for (int off = 32; off; off >>= 1) mx = fmaxf(mx, __shfl_xor(mx, off));
        float e[4], s = 0.0f;
        #pragma unroll
        for (int q = 0; q < 4; ++q) {
            e[q] = (x[q] > -INFINITY) ? __expf(x[q] - mx) : 0.0f;
            s += e[q];
        }
        #pragma unroll
        for (int off = 32; off; off >>= 1) s += __shfl_xor(s, off);
        float inv = 1.0f / s;
        uint2 wv;
        wv.x = (unsigned)f2bf(e[0] * inv) | ((unsigned)f2bf(e[1] * inv) << 16);
        wv.y = (unsigned)f2bf(e[2] * inv) | ((unsigned)f2bf(e[3] * inv) << 16);
        int wo = (lane * 8) ^ ((hl & 7) << 4);
        *(uint2*)(Wl + hl * 512 + wo) = wv;
    }
    __syncthreads();

    f32x4 acc[4][4];
    #pragma unroll
    for (int mb = 0; mb < 4; ++mb)
        #pragma unroll
        for (int nk = 0; nk < 4; ++nk) acc[mb][nk] = (f32x4){0.f, 0.f, 0.f, 0.f};

    #pragma unroll
    for (int ks = 0; ks < 8; ++ks) {
        bf16x8 fa[4], fb[4];
        #pragma unroll
        for (int mb = 0; mb < 4; ++mb)
            fa[mb] = *(const bf16x8*)(seqb + (size_t)(bq * 64 + mb * 16 + l15) * NSEQ + ks * 32 + lg * 8);
        #pragma unroll
        for (int nk = 0; nk < 4; ++nk) {
            int hrow = hhalf * 64 + nk * 16 + l15;
            int co = (ks * 64 + lg * 16) ^ ((hrow & 7) << 4);
            fb[nk] = *(const bf16x8*)(Wl + hrow * 512 + co);
        }
        #pragma unroll
        for (int mb = 0; mb < 4; ++mb)
            #pragma unroll
            for (int nk = 0; nk < 4; ++nk)
                acc[mb][nk] = __builtin_amdgcn_mfma_f32_16x16x32_bf16(fa[mb], fb[nk], acc[mb][nk], 0, 0, 0);
    }

    #pragma unroll
    for (int mb = 0; mb < 4; ++mb)
        #pragma unroll
        for (int r = 0; r < 4; ++r) {
            int b = bq * 64 + mb * 16 + lg * 4 + r;
            size_t base = ((size_t)m * BB + b) * HDIM + ht * 128 + hhalf * 64 + l15;
            unsigned p01 = cvtpk8(acc[mb][0][r], acc[mb][1][r]);
            unsigned p23 = cvtpk8(acc[mb][2][r], acc[mb][3][r]);
            hat8[base +  0] = (unsigned char)(p01 & 0xff);
            hat8[base + 16] = (unsigned char)((p01 >> 8) & 0xff);
            hat8[base + 32] = (unsigned char)(p23 & 0xff);
            hat8[base + 48] = (unsigned char)((p23 >> 8) & 0xff);
        }
}

// Logits GEMM, fp8, barrier-free: A = 64 b-rows x 512 h fp8 in LDS (32 KB,
// full 4-bit granule swizzle, conflict-free). B fragments = 2x dwordx4 L2 loads
// per kstep from k-permuted phi8, 1-deep prefetch. setprio(1) on MFMA cluster.
__global__ __launch_bounds__(512, 4) void kernD(const unsigned char* __restrict__ hat8,
                                                const unsigned char* __restrict__ phi8,
                                                const int* __restrict__ indices,
                                                float* __restrict__ pmax,
                                                float* __restrict__ psum,
                                                int* __restrict__ parg,
                                                float* __restrict__ ptgt) {
    // XCD-chunked decode: 16 consecutive blocks (one m) per XCD position
    int id = blockIdx.x;                    // 0..4079
    int c = id & 7, pos = id >> 3;
    int lin = c * 510 + pos;                // bijective (4080 = 8*510)
    int m = lin >> 4, sub = lin & 15;
    int bblk = sub >> 2, kblk = sub & 3;

    int t = threadIdx.x, l = t & 63, w = t >> 6;   // w = k-slice index
    int l15 = l & 15, lg = l >> 4;

    __shared__ char Al[64 * 512];           // 32 KB fp8 A panel
    __shared__ int idx_s[64];

    // one-time A stage (reg-staged): granule g of row r stored at gx = g^(r&15).
    const unsigned char* Ab = hat8 + ((size_t)m * BB + bblk * 64) * HDIM;
    #pragma unroll
    for (int i = 0; i < 4; ++i) {
        int row = w * 8 + i * 2 + (l >> 5);
        int col16 = l & 31;
        int4 v = *(const int4*)(Ab + (size_t)row * 512 + col16 * 16);
        if (row & 1) { int tx = v.x, ty = v.y; v.x = v.z; v.y = v.w; v.z = tx; v.w = ty; }
        int pairbase = (col16 * 2) ^ (row & 14);
        *(int4*)(Al + row * 512 + pairbase * 8) = v;
    }
    if (t < 64) idx_s[t] = indices[bblk * 64 + t];
    __syncthreads();

    int kb = kblk * 512 + w * 64;           // this wave's k base
    // k-permuted phi8: granules for (nk=0,k=kb+l15) and (nk=1,k=kb+16+l15) are
    // adjacent at granule kb + 2*l15; nk=2,3 at +32 granules (=+256 B).
    const unsigned char* Bp = phi8 + ((size_t)lg * KDS + kb + 2 * l15) * 8;

    f32x4 acc[4][4];
    #pragma unroll
    for (int mb = 0; mb < 4; ++mb)
        #pragma unroll
        for (int nk = 0; nk < 4; ++nk) acc[mb][nk] = (f32x4){0.f, 0.f, 0.f, 0.f};

    i64x2 nbA = *(const i64x2*)(Bp);
    i64x2 nbB = *(const i64x2*)(Bp + 256);

    #pragma unroll
    for (int kstep = 0; kstep < 16; ++kstep) {
        i64x2 fbA = nbA, fbB = nbB;
        if (kstep < 15) {
            Bp += 65536;                    // 4*KDS*8 bytes
            nbA = *(const i64x2*)(Bp);
            nbB = *(const i64x2*)(Bp + 256);
        }
        int gx = (kstep * 4 + lg) ^ l15;    // full 4-bit swizzle: conflict-free
        i64 fa[4];
        #pragma unroll
        for (int mb = 0; mb < 4; ++mb)
            fa[mb] = *(const i64*)(Al + (mb * 16 + l15) * 512 + gx * 8);
        __builtin_amdgcn_s_setprio(1);
        #pragma unroll
        for (int mb = 0; mb < 4; ++mb) {
            acc[mb][0] = __builtin_amdgcn_mfma_f32_16x16x32_fp8_fp8(fa[mb], fbA[0], acc[mb][0], 0, 0, 0);
            acc[mb][1] = __builtin_amdgcn_mfma_f32_16x16x32_fp8_fp8(fa[mb], fbA[1], acc[mb][1], 0, 0, 0);
            acc[mb][2] = __builtin_amdgcn_mfma_f32_16x16x32_fp8_fp8(fa[mb], fbB[0], acc[mb][2], 0, 0, 0);
            acc[mb][3] = __builtin_amdgcn_mfma_f32_16x16x32_fp8_fp8(fa[mb], fbB[1], acc[mb][3], 0, 0, 0);
        }
        __builtin_amdgcn_s_setprio(0);
    }

    // epilogue: two-pass per b-row (max -> sumexp), cndmask argmax, 1 ptgt store
    #pragma unroll
    for (int mb = 0; mb < 4; ++mb) {
        #pragma unroll
        for (int r = 0; r < 4; ++r) {
            int row_local = mb * 16 + lg * 4 + r;         // 0..63
            int bg = bblk * 64 + row_local;               // b 0..255
            int ib = idx_s[row_local];
            float a0 = acc[mb][0][r], a1 = acc[mb][1][r];
            float a2 = acc[mb][2][r], a3 = acc[mb][3][r];
            float M = fmaxf(fmaxf(a0, a1), fmaxf(a2, a3));
            #pragma unroll
            for (int off = 1; off < 16; off <<= 1) M = fmaxf(M, __shfl_xor(M, off));
            float S = __expf(a0 - M) + __expf(a1 - M) + __expf(a2 - M) + __expf(a3 - M);
            #pragma unroll
            for (int off = 1; off < 16; off <<= 1) S += __shfl_xor(S, off);
            int KA = 0x7fffffff;
            KA = (a3 == M) ? (kb + 48 + l15) : KA;
            KA = (a2 == M) ? (kb + 32 + l15) : KA;
            KA = (a1 == M) ? (kb + 16 + l15) : KA;
            KA = (a0 == M) ? (kb + l15) : KA;
            #pragma unroll
            for (int off = 1; off < 16; off <<= 1) {
                int ok = __shfl_xor(KA, off);
                KA = ok < KA ? ok : KA;
            }
            int d = ib - kb;
            if ((unsigned)d < 64u && (d & 15) == l15) {
                float s0 = (d & 16) ? a1 : a0;
                float s1 = (d & 16) ? a3 : a2;
                ptgt[m * BB + bg] = (d & 32) ? s1 : s0;
            }
            if (l15 == 0) {
                size_t pidx = ((size_t)m * BB + bg) * 32 + kblk * 8 + w;   // ascending k
                pmax[pidx] = M;
                psum[pidx] = S;
                parg[pidx] = KA;
            }
        }
    }
}

// combine 32 k-range partials per (m,b) -> CE + accuracy sums
__global__ __launch_bounds__(256) void kernE(const float* __restrict__ pmax,
                                             const float* __restrict__ psum,
                                             const int* __restrict__ parg,
                                             const float* __restrict__ ptgt,
                                             const int* __restrict__ indices,
                                             float* __restrict__ accum) {
    int m = blockIdx.x, b = threadIdx.x;
    size_t base = ((size_t)m * BB + b) * 32;
    float M = -INFINITY, S = 0.0f;
    int KA = 0;
    #pragma unroll 4
    for (int kb = 0; kb < 32; ++kb) {       // ascending k: strict > keeps first-index ties
        float om = pmax[base + kb], os = psum[base + kb];
        int ok = parg[base + kb];
        float Mn = fmaxf(M, om);
        S = S * __expf(M - Mn) + os * __expf(om - Mn);
        if (om > M) KA = ok;
        M = Mn;
    }
    float ce = M + logf(S) - ptgt[(size_t)m * BB + b];
    float corr = (KA == indices[b]) ? 1.0f : 0.0f;
    #pragma unroll
    for (int off = 32; off; off >>= 1) { ce += __shfl_xor(ce, off); corr += __shfl_xor(corr, off); }
    __shared__ float rc[4], rr[4];
    int wv = b >> 6;
    if ((b & 63) == 0) { rc[wv] = ce; rr[wv] = corr; }
    __syncthreads();
    if (b == 0) {
        atomicAdd(&accum[0], rc[0] + rc[1] + rc[2] + rc[3]);
        atomicAdd(&accum[1], rr[0] + rr[1] + rr[2] + rr[3]);
    }
}

__global__ void kfin(const float* __restrict__ accum, float* __restrict__ out) {
    if (threadIdx.x == 0) {
        const float inv = 1.0f / (255.0f * 256.0f);
        out[0] = accum[0] * inv;
        out[1] = accum[1] * inv;
    }
}

extern "C" void kernel_launch(void* const* d_in, const int* in_sizes, int n_in,
                              void* d_out, int out_size, void* d_ws, size_t ws_size,
                              hipStream_t stream) {
    const float* A_logits = (const float*)d_in[0];   // (256,512,256)
    const float* B_logits = (const float*)d_in[1];   // (512,256)
    const float* sequences = (const float*)d_in[2];  // (256,256)
    const float* dataset = (const float*)d_in[3];    // (2048,256)
    const int* indices = (const int*)d_in[4];        // (256,)
    float* out = (float*)d_out;

    float* ws = (float*)d_ws;
    float* accum = ws + OFF_ACC;
    float* pmax = ws + OFF_PMAX;
    float* psum = ws + OFF_PSUM;
    int* parg = (int*)(ws + OFF_PARG);
    float* ptgt = ws + OFF_PTGT;
    ushort* dsb = (ushort*)(ws + OFF_DSB);
    ushort* seqb = (ushort*)(ws + OFF_SEQB);
    ushort* wBb = (ushort*)(ws + OFF_WBB);
    unsigned char* phi8 = (unsigned char*)(ws + OFF_PHI8);
    unsigned char* hat8 = (unsigned char*)(ws + OFF_HAT8);

    kzero<<<1, 64, 0, stream>>>(accum);
    kernT2<<<(KDS * NSEQ) / 256, 256, 0, stream>>>(dataset, sequences, dsb, seqb);
    kernSB<<<HDIM / 4, 256, 0, stream>>>(B_logits, wBb);
    kernP<<<dim3(KDS / 128, HDIM / 128), 256, 0, stream>>>(dsb, wBb, phi8);
    kernC2<<<dim3(NM, HDIM / 128), 512, 0, stream>>>(A_logits, seqb, hat8);
    kernD<<<NM * 16, 512, 0, stream>>>(hat8, phi8, indices, pmax, psum, parg, ptgt);
    kernE<<<NM, 256, 0, stream>>>(pmax, psum, parg, ptgt, indices, accum);
    kfin<<<1, 64, 0, stream>>>(accum, out);
}

// Round 17
// 218.874 us; speedup vs baseline: 1.3856x; 1.0018x over previous
//
#include <hip/hip_runtime.h>
#include <math.h>

// Problem constants (reference: N=256, H=512, K=2048, B=256, ETA=1.0)
#define NSEQ 256
#define HDIM 512
#define KDS  2048
#define BB   256
#define NM   255   // N-1 prefix rows

typedef __attribute__((ext_vector_type(8))) short bf16x8;
typedef __attribute__((ext_vector_type(4))) float f32x4;
typedef long i64;
typedef __attribute__((ext_vector_type(2))) long i64x2;

// ---------------- workspace layout (float slots) ----------------
#define OFF_ACC   0            //        16
#define OFF_P4    16           // 8,355,840  packed partials [m][b][32][4] = (M,S,KAbits,pad)
#define OFF_PTGT  8355856      //    65,280  target logit per (m,b)
#define OFF_DSB   8421136      //   262,144 f32 slots = 524,288 bf16 dataset [k][n]
#define OFF_SEQB  8683280      //    32,768 f32 slots = 65,536 bf16 seq [b][j]
#define OFF_WBB   8716048      //    65,536 f32 slots = 131,072 bf16 softmax(B_logits) [h][n]
#define OFF_PHI8  8781584      //   262,144 f32 slots = 1,048,576 fp8 phi [h/8][kperm][8]
#define OFF_HAT8  9043728      // 8,355,840 f32 slots = 33,423,360 fp8 hat [m][b][h]
// end: 17,399,568 floats = 69.6 MB (< 140 MB proven available)

__device__ __forceinline__ ushort f2bf(float f) {
    unsigned u = __float_as_uint(f);
    unsigned r = (u + 0x7fffu + ((u >> 16) & 1u)) >> 16;   // RNE; NaN impossible here
    return (ushort)r;
}

// HW fp8 e4m3fn convert: 2 floats -> 2 bytes (low word), RNE
__device__ __forceinline__ unsigned cvtpk8(float a, float b) {
    return (unsigned)__builtin_amdgcn_cvt_pk_fp8_f32(a, b, 0, false);
}

__global__ void kzero(float* a) {
    if (threadIdx.x < 16) a[threadIdx.x] = 0.0f;
}

// convert dataset (K,N) and sequences (B,N) f32 -> bf16, same layouts
__global__ __launch_bounds__(256) void kernT2(const float* __restrict__ ds,
                                              const float* __restrict__ seq,
                                              ushort* __restrict__ dsb,
                                              ushort* __restrict__ seqb) {
    int id = blockIdx.x * 256 + threadIdx.x;      // grid covers KDS*NSEQ exactly
    dsb[id] = f2bf(ds[id]);
    if (id < BB * NSEQ) seqb[id] = f2bf(seq[id]);
}

// softmax each row of B_logits (512 x 256) -> bf16 wBb [h][n]
__global__ __launch_bounds__(256) void kernSB(const float* __restrict__ B_logits,
                                              ushort* __restrict__ wBb) {
    int w = threadIdx.x >> 6, l = threadIdx.x & 63;
    int h = blockIdx.x * 4 + w;
    float4 v = ((const float4*)(B_logits + (size_t)h * NSEQ))[l];
    float mx = fmaxf(fmaxf(v.x, v.y), fmaxf(v.z, v.w));
    #pragma unroll
    for (int off = 32; off; off >>= 1) mx = fmaxf(mx, __shfl_xor(mx, off));
    float e[4] = {__expf(v.x - mx), __expf(v.y - mx), __expf(v.z - mx), __expf(v.w - mx)};
    float s = e[0] + e[1] + e[2] + e[3];
    #pragma unroll
    for (int off = 32; off; off >>= 1) s += __shfl_xor(s, off);
    float inv = 1.0f / s;
    uint2 o;
    o.x = (unsigned)f2bf(e[0] * inv) | ((unsigned)f2bf(e[1] * inv) << 16);
    o.y = (unsigned)f2bf(e[2] * inv) | ((unsigned)f2bf(e[3] * inv) << 16);
    *(uint2*)(wBb + (size_t)h * NSEQ + l * 4) = o;
}

// phi GEMM: phi[k][h] = sum_n dsb[k][n] * wBb[h][n]; epilogue writes fp8 phi8 at
// k-permuted position S(k) = (k&~31) + ((k&15)<<1) + ((k>>4)&1) so kernD's
// fb loads for nk=0,1 (and 2,3) are 16B contiguous -> dwordx4.
#define LDST 144
__global__ __launch_bounds__(256) void kernP(const ushort* __restrict__ dsb,
                                             const ushort* __restrict__ wBb,
                                             unsigned char* __restrict__ phi8) {
    int kblk = blockIdx.x, hblk = blockIdx.y;
    int t = threadIdx.x, lane = t & 63, wave = t >> 6;
    int bhalf = wave & 1, khalf = wave >> 1;
    __shared__ int4 Al4[128 * LDST / 16];
    __shared__ int4 Bl4[128 * LDST / 16];
    char* Al = (char*)Al4;
    char* Bl = (char*)Bl4;
    f32x4 acc[4][4];
    #pragma unroll
    for (int mb = 0; mb < 4; ++mb)
        #pragma unroll
        for (int nk = 0; nk < 4; ++nk) acc[mb][nk] = (f32x4){0.f, 0.f, 0.f, 0.f};
    const ushort* Abase = dsb + (size_t)kblk * 128 * NSEQ;
    const ushort* Bbase = wBb + (size_t)hblk * 128 * NSEQ;
    int l15 = lane & 15, lg = lane >> 4;
    for (int n0 = 0; n0 < NSEQ; n0 += 64) {
        #pragma unroll
        for (int i = 0; i < 4; ++i) {
            int c = i * 256 + t;
            int row = c >> 3, c8 = c & 7;
            int4 va = *(const int4*)(Abase + (size_t)row * NSEQ + n0 + c8 * 8);
            int4 vb = *(const int4*)(Bbase + (size_t)row * NSEQ + n0 + c8 * 8);
            *(int4*)(Al + row * LDST + c8 * 16) = va;
            *(int4*)(Bl + row * LDST + c8 * 16) = vb;
        }
        __syncthreads();
        #pragma unroll
        for (int ks = 0; ks < 2; ++ks) {
            bf16x8 fa[4], fb[4];
            #pragma unroll
            for (int mb = 0; mb < 4; ++mb)
                fa[mb] = *(const bf16x8*)(Al + (bhalf * 64 + mb * 16 + l15) * LDST + ks * 64 + lg * 16);
            #pragma unroll
            for (int nk = 0; nk < 4; ++nk)
                fb[nk] = *(const bf16x8*)(Bl + (khalf * 64 + nk * 16 + l15) * LDST + ks * 64 + lg * 16);
            #pragma unroll
            for (int mb = 0; mb < 4; ++mb)
                #pragma unroll
                for (int nk = 0; nk < 4; ++nk)
                    acc[mb][nk] = __builtin_amdgcn_mfma_f32_16x16x32_bf16(fa[mb], fb[nk], acc[mb][nk], 0, 0, 0);
        }
        __syncthreads();
    }
    #pragma unroll
    for (int mb = 0; mb < 4; ++mb)
        #pragma unroll
        for (int r = 0; r < 4; ++r) {
            int k = kblk * 128 + bhalf * 64 + mb * 16 + lg * 4 + r;
            int sk = (k & ~31) + ((k & 15) << 1) + ((k >> 4) & 1);   // bijective perm
            unsigned p01 = cvtpk8(acc[mb][0][r], acc[mb][1][r]);
            unsigned p23 = cvtpk8(acc[mb][2][r], acc[mb][3][r]);
            #pragma unroll
            for (int nk = 0; nk < 4; ++nk) {
                int h = hblk * 128 + khalf * 64 + nk * 16 + l15;
                unsigned byte = (nk < 2) ? ((nk & 1) ? (p01 >> 8) : p01)
                                         : ((nk & 1) ? (p23 >> 8) : p23);
                phi8[((size_t)(h >> 3) * KDS + sk) * 8 + (h & 7)] = (unsigned char)(byte & 0xff);
            }
        }
}

// Fused: masked softmax of A_logits[m+1, ht*128..+128, :] -> bf16 weights in LDS,
// then MFMA  hat[b][h] = sum_j seq[b][j] * W[h][j]  -> hat8 fp8 [m][b][h].
__global__ __launch_bounds__(512) void kernC2(const float* __restrict__ A_logits,
                                              const ushort* __restrict__ seqb,
                                              unsigned char* __restrict__ hat8) {
    int m = blockIdx.x, ht = blockIdx.y;
    int t = threadIdx.x, lane = t & 63, wave = t >> 6;
    int bq = wave & 3, hhalf = wave >> 2;
    int l15 = lane & 15, lg = lane >> 4;
    __shared__ int4 Wl4[128 * 512 / 16];   // 64 KB
    char* Wl = (char*)Wl4;

    for (int rr = 0; rr < 16; ++rr) {
        int hl = wave + rr * 8;
        const float4* row = (const float4*)(A_logits + ((size_t)(m + 1) * HDIM + ht * 128 + hl) * NSEQ);
        float4 v = row[lane];
        int j0 = lane * 4;
        float x[4];
        x[0] = (j0 + 0 <= m) ? v.x : -INFINITY;
        x[1] = (j0 + 1 <= m) ? v.y : -INFINITY;
        x[2] = (j0 + 2 <= m) ? v.z : -INFINITY;
        x[3] = (j0 + 3 <= m) ? v.w : -INFINITY;
        float mx = fmaxf(fmaxf(x[0], x[1]), fmaxf(x[2], x[3]));
        #pragma unroll
        for (int off = 32; off; off >>= 1) mx = fmaxf(mx, __shfl_xor(mx, off));
        float e[4], s = 0.0f;
        #pragma unroll
        for (int q = 0; q < 4; ++q) {
            e[q] = (x[q] > -INFINITY) ? __expf(x[q] - mx) : 0.0f;
            s += e[q];
        }
        #pragma unroll
        for (int off = 32; off; off >>= 1) s += __shfl_xor(s, off);
        float inv = 1.0f / s;
        uint2 wv;
        wv.x = (unsigned)f2bf(e[0] * inv) | ((unsigned)f2bf(e[1] * inv) << 16);
        wv.y = (unsigned)f2bf(e[2] * inv) | ((unsigned)f2bf(e[3] * inv) << 16);
        int wo = (lane * 8) ^ ((hl & 7) << 4);
        *(uint2*)(Wl + hl * 512 + wo) = wv;
    }
    __syncthreads();

    f32x4 acc[4][4];
    #pragma unroll
    for (int mb = 0; mb < 4; ++mb)
        #pragma unroll
        for (int nk = 0; nk < 4; ++nk) acc[mb][nk] = (f32x4){0.f, 0.f, 0.f, 0.f};

    #pragma unroll
    for (int ks = 0; ks < 8; ++ks) {
        bf16x8 fa[4], fb[4];
        #pragma unroll
        for (int mb = 0; mb < 4; ++mb)
            fa[mb] = *(const bf16x8*)(seqb + (size_t)(bq * 64 + mb * 16 + l15) * NSEQ + ks * 32 + lg * 8);
        #pragma unroll
        for (int nk = 0; nk < 4; ++nk) {
            int hrow = hhalf * 64 + nk * 16 + l15;
            int co = (ks * 64 + lg * 16) ^ ((hrow & 7) << 4);
            fb[nk] = *(const bf16x8*)(Wl + hrow * 512 + co);
        }
        #pragma unroll
        for (int mb = 0; mb < 4; ++mb)
            #pragma unroll
            for (int nk = 0; nk < 4; ++nk)
                acc[mb][nk] = __builtin_amdgcn_mfma_f32_16x16x32_bf16(fa[mb], fb[nk], acc[mb][nk], 0, 0, 0);
    }

    #pragma unroll
    for (int mb = 0; mb < 4; ++mb)
        #pragma unroll
        for (int r = 0; r < 4; ++r) {
            int b = bq * 64 + mb * 16 + lg * 4 + r;
            size_t base = ((size_t)m * BB + b) * HDIM + ht * 128 + hhalf * 64 + l15;
            unsigned p01 = cvtpk8(acc[mb][0][r], acc[mb][1][r]);
            unsigned p23 = cvtpk8(acc[mb][2][r], acc[mb][3][r]);
            hat8[base +  0] = (unsigned char)(p01 & 0xff);
            hat8[base + 16] = (unsigned char)((p01 >> 8) & 0xff);
            hat8[base + 32] = (unsigned char)(p23 & 0xff);
            hat8[base + 48] = (unsigned char)((p23 >> 8) & 0xff);
        }
}

// Logits GEMM, fp8, barrier-free: A = 64 b-rows x 512 h fp8 in LDS (32 KB,
// full 4-bit granule swizzle, conflict-free). B fragments = 2x dwordx4 L2 loads
// per kstep (k-permuted phi8) with 2-DEEP 3-set register rotation. setprio on
// MFMA cluster. Partials: ONE float4 store per row.
__global__ __launch_bounds__(512, 4) void kernD(const unsigned char* __restrict__ hat8,
                                                const unsigned char* __restrict__ phi8,
                                                const int* __restrict__ indices,
                                                float* __restrict__ p4,
                                                float* __restrict__ ptgt) {
    // XCD-chunked decode: 16 consecutive blocks (one m) per XCD position
    int id = blockIdx.x;                    // 0..4079
    int c = id & 7, pos = id >> 3;
    int lin = c * 510 + pos;                // bijective (4080 = 8*510)
    int m = lin >> 4, sub = lin & 15;
    int bblk = sub >> 2, kblk = sub & 3;

    int t = threadIdx.x, l = t & 63, w = t >> 6;   // w = k-slice index
    int l15 = l & 15, lg = l >> 4;

    __shared__ char Al[64 * 512];           // 32 KB fp8 A panel
    __shared__ int idx_s[64];

    // one-time A stage (reg-staged): granule g of row r stored at gx = g^(r&15).
    const unsigned char* Ab = hat8 + ((size_t)m * BB + bblk * 64) * HDIM;
    #pragma unroll
    for (int i = 0; i < 4; ++i) {
        int row = w * 8 + i * 2 + (l >> 5);
        int col16 = l & 31;
        int4 v = *(const int4*)(Ab + (size_t)row * 512 + col16 * 16);
        if (row & 1) { int tx = v.x, ty = v.y; v.x = v.z; v.y = v.w; v.z = tx; v.w = ty; }
        int pairbase = (col16 * 2) ^ (row & 14);
        *(int4*)(Al + row * 512 + pairbase * 8) = v;
    }
    if (t < 64) idx_s[t] = indices[bblk * 64 + t];
    __syncthreads();

    int kb = kblk * 512 + w * 64;           // this wave's k base
    const unsigned char* Bp = phi8 + ((size_t)lg * KDS + kb + 2 * l15) * 8;

    f32x4 acc[4][4];
    #pragma unroll
    for (int mb = 0; mb < 4; ++mb)
        #pragma unroll
        for (int nk = 0; nk < 4; ++nk) acc[mb][nk] = (f32x4){0.f, 0.f, 0.f, 0.f};

    // 3-set, 2-deep fb rotation (sets are 8 VGPR each at fp8 size)
    i64x2 s0a, s0b, s1a, s1b, s2a, s2b;
    s0a = *(const i64x2*)(Bp);
    s0b = *(const i64x2*)(Bp + 256);
    s1a = *(const i64x2*)(Bp + 65536);
    s1b = *(const i64x2*)(Bp + 65536 + 256);

#define DSTEP(K, CA, CB, NA, NB)                                              \
    {                                                                         \
        if ((K) < 14) {                                                       \
            const unsigned char* p_ = Bp + (size_t)((K) + 2) * 65536;         \
            NA = *(const i64x2*)(p_);                                         \
            NB = *(const i64x2*)(p_ + 256);                                   \
        }                                                                     \
        int gx = ((K) * 4 + lg) ^ l15;                                        \
        i64 fa0 = *(const i64*)(Al + (0 * 16 + l15) * 512 + gx * 8);          \
        i64 fa1 = *(const i64*)(Al + (1 * 16 + l15) * 512 + gx * 8);          \
        i64 fa2 = *(const i64*)(Al + (2 * 16 + l15) * 512 + gx * 8);          \
        i64 fa3 = *(const i64*)(Al + (3 * 16 + l15) * 512 + gx * 8);          \
        __builtin_amdgcn_s_setprio(1);                                        \
        acc[0][0] = __builtin_amdgcn_mfma_f32_16x16x32_fp8_fp8(fa0, CA[0], acc[0][0], 0, 0, 0); \
        acc[0][1] = __builtin_amdgcn_mfma_f32_16x16x32_fp8_fp8(fa0, CA[1], acc[0][1], 0, 0, 0); \
        acc[0][2] = __builtin_amdgcn_mfma_f32_16x16x32_fp8_fp8(fa0, CB[0], acc[0][2], 0, 0, 0); \
        acc[0][3] = __builtin_amdgcn_mfma_f32_16x16x32_fp8_fp8(fa0, CB[1], acc[0][3], 0, 0, 0); \
        acc[1][0] = __builtin_amdgcn_mfma_f32_16x16x32_fp8_fp8(fa1, CA[0], acc[1][0], 0, 0, 0); \
        acc[1][1] = __builtin_amdgcn_mfma_f32_16x16x32_fp8_fp8(fa1, CA[1], acc[1][1], 0, 0, 0); \
        acc[1][2] = __builtin_amdgcn_mfma_f32_16x16x32_fp8_fp8(fa1, CB[0], acc[1][2], 0, 0, 0); \
        acc[1][3] = __builtin_amdgcn_mfma_f32_16x16x32_fp8_fp8(fa1, CB[1], acc[1][3], 0, 0, 0); \
        acc[2][0] = __builtin_amdgcn_mfma_f32_16x16x32_fp8_fp8(fa2, CA[0], acc[2][0], 0, 0, 0); \
        acc[2][1] = __builtin_amdgcn_mfma_f32_16x16x32_fp8_fp8(fa2, CA[1], acc[2][1], 0, 0, 0); \
        acc[2][2] = __builtin_amdgcn_mfma_f32_16x16x32_fp8_fp8(fa2, CB[0], acc[2][2], 0, 0, 0); \
        acc[2][3] = __builtin_amdgcn_mfma_f32_16x16x32_fp8_fp8(fa2, CB[1], acc[2][3], 0, 0, 0); \
        acc[3][0] = __builtin_amdgcn_mfma_f32_16x16x32_fp8_fp8(fa3, CA[0], acc[3][0], 0, 0, 0); \
        acc[3][1] = __builtin_amdgcn_mfma_f32_16x16x32_fp8_fp8(fa3, CA[1], acc[3][1], 0, 0, 0); \
        acc[3][2] = __builtin_amdgcn_mfma_f32_16x16x32_fp8_fp8(fa3, CB[0], acc[3][2], 0, 0, 0); \
        acc[3][3] = __builtin_amdgcn_mfma_f32_16x16x32_fp8_fp8(fa3, CB[1], acc[3][3], 0, 0, 0); \
        __builtin_amdgcn_s_setprio(0);                                        \
    }

    DSTEP(0,  s0a, s0b, s2a, s2b)
    DSTEP(1,  s1a, s1b, s0a, s0b)
    DSTEP(2,  s2a, s2b, s1a, s1b)
    DSTEP(3,  s0a, s0b, s2a, s2b)
    DSTEP(4,  s1a, s1b, s0a, s0b)
    DSTEP(5,  s2a, s2b, s1a, s1b)
    DSTEP(6,  s0a, s0b, s2a, s2b)
    DSTEP(7,  s1a, s1b, s0a, s0b)
    DSTEP(8,  s2a, s2b, s1a, s1b)
    DSTEP(9,  s0a, s0b, s2a, s2b)
    DSTEP(10, s1a, s1b, s0a, s0b)
    DSTEP(11, s2a, s2b, s1a, s1b)
    DSTEP(12, s0a, s0b, s2a, s2b)
    DSTEP(13, s1a, s1b, s0a, s0b)
    DSTEP(14, s2a, s2b, s1a, s1b)
    DSTEP(15, s0a, s0b, s1a, s1b)
#undef DSTEP

    // epilogue: two-pass per b-row (max -> sumexp), cndmask argmax, 1 ptgt store,
    // ONE packed float4 partial store per row
    #pragma unroll
    for (int mb = 0; mb < 4; ++mb) {
        #pragma unroll
        for (int r = 0; r < 4; ++r) {
            int row_local = mb * 16 + lg * 4 + r;         // 0..63
            int bg = bblk * 64 + row_local;               // b 0..255
            int ib = idx_s[row_local];
            float a0 = acc[mb][0][r], a1 = acc[mb][1][r];
            float a2 = acc[mb][2][r], a3 = acc[mb][3][r];
            float M = fmaxf(fmaxf(a0, a1), fmaxf(a2, a3));
            #pragma unroll
            for (int off = 1; off < 16; off <<= 1) M = fmaxf(M, __shfl_xor(M, off));
            float S = __expf(a0 - M) + __expf(a1 - M) + __expf(a2 - M) + __expf(a3 - M);
            #pragma unroll
            for (int off = 1; off < 16; off <<= 1) S += __shfl_xor(S, off);
            int KA = 0x7fffffff;
            KA = (a3 == M) ? (kb + 48 + l15) : KA;
            KA = (a2 == M) ? (kb + 32 + l15) : KA;
            KA = (a1 == M) ? (kb + 16 + l15) : KA;
            KA = (a0 == M) ? (kb + l15) : KA;
            #pragma unroll
            for (int off = 1; off < 16; off <<= 1) {
                int ok = __shfl_xor(KA, off);
                KA = ok < KA ? ok : KA;
            }
            int d = ib - kb;
            if ((unsigned)d < 64u && (d & 15) == l15) {
                float s0 = (d & 16) ? a1 : a0;
                float s1 = (d & 16) ? a3 : a2;
                ptgt[m * BB + bg] = (d & 32) ? s1 : s0;
            }
            if (l15 == 0) {
                size_t pidx = (((size_t)m * BB + bg) * 32 + kblk * 8 + w) * 4;
                float4 pv;
                pv.x = M; pv.y = S; pv.z = __int_as_float(KA); pv.w = 0.0f;
                *(float4*)(p4 + pidx) = pv;
            }
        }
    }
}

// combine 32 packed partials per (m,b) -> CE + accuracy sums (two-pass: no exp
// in the max/argmax pass, 32 exps in the sum pass)
__global__ __launch_bounds__(256) void kernE(const float* __restrict__ p4,
                                             const float* __restrict__ ptgt,
                                             const int* __restrict__ indices,
                                             float* __restrict__ accum) {
    int m = blockIdx.x, b = threadIdx.x;
    const float4* base = (const float4*)(p4 + ((size_t)m * BB + b) * 32 * 4);
    float M = -INFINITY;
    int KA = 0;
    #pragma unroll 4
    for (int kb = 0; kb < 32; ++kb) {       // ascending k: strict > keeps first-index ties
        float4 v = base[kb];
        if (v.x > M) { M = v.x; KA = __float_as_int(v.z); }
    }
    float S = 0.0f;
    #pragma unroll 4
    for (int kb = 0; kb < 32; ++kb) {
        float4 v = base[kb];
        S += v.y * __expf(v.x - M);
    }
    float ce = M + logf(S) - ptgt[(size_t)m * BB + b];
    float corr = (KA == indices[b]) ? 1.0f : 0.0f;
    #pragma unroll
    for (int off = 32; off; off >>= 1) { ce += __shfl_xor(ce, off); corr += __shfl_xor(corr, off); }
    __shared__ float rc[4], rr[4];
    int wv = b >> 6;
    if ((b & 63) == 0) { rc[wv] = ce; rr[wv] = corr; }
    __syncthreads();
    if (b == 0) {
        atomicAdd(&accum[0], rc[0] + rc[1] + rc[2] + rc[3]);
        atomicAdd(&accum[1], rr[0] + rr[1] + rr[2] + rr[3]);
    }
}

__global__ void kfin(const float* __restrict__ accum, float* __restrict__ out) {
    if (threadIdx.x == 0) {
        const float inv = 1.0f / (255.0f * 256.0f);
        out[0] = accum[0] * inv;
        out[1] = accum[1] * inv;
    }
}

extern "C" void kernel_launch(void* const* d_in, const int* in_sizes, int n_in,
                              void* d_out, int out_size, void* d_ws, size_t ws_size,
                              hipStream_t stream) {
    const float* A_logits = (const float*)d_in[0];   // (256,512,256)
    const float* B_logits = (const float*)d_in[1];   // (512,256)
    const float* sequences = (const float*)d_in[2];  // (256,256)
    const float* dataset = (const float*)d_in[3];    // (2048,256)
    const int* indices = (const int*)d_in[4];        // (256,)
    float* out = (float*)d_out;

    float* ws = (float*)d_ws;
    float* accum = ws + OFF_ACC;
    float* p4 = ws + OFF_P4;
    float* ptgt = ws + OFF_PTGT;
    ushort* dsb = (ushort*)(ws + OFF_DSB);
    ushort* seqb = (ushort*)(ws + OFF_SEQB);
    ushort* wBb = (ushort*)(ws + OFF_WBB);
    unsigned char* phi8 = (unsigned char*)(ws + OFF_PHI8);
    unsigned char* hat8 = (unsigned char*)(ws + OFF_HAT8);

    kzero<<<1, 64, 0, stream>>>(accum);
    kernT2<<<(KDS * NSEQ) / 256, 256, 0, stream>>>(dataset, sequences, dsb, seqb);
    kernSB<<<HDIM / 4, 256, 0, stream>>>(B_logits, wBb);
    kernP<<<dim3(KDS / 128, HDIM / 128), 256, 0, stream>>>(dsb, wBb, phi8);
    kernC2<<<dim3(NM, HDIM / 128), 512, 0, stream>>>(A_logits, seqb, hat8);
    kernD<<<NM * 16, 512, 0, stream>>>(hat8, phi8, indices, p4, ptgt);
    kernE<<<NM, 256, 0, stream>>>(p4, ptgt, indices, accum);
    kfin<<<1, 64, 0, stream>>>(accum, out);
}